// Round 1
// baseline (291.979 us; speedup 1.0000x reference)
//
#include <hip/hip_runtime.h>
#include <stdint.h>

typedef __attribute__((ext_vector_type(8))) __bf16 bf16x8;
typedef __attribute__((ext_vector_type(16))) float f32x16;

__device__ __forceinline__ unsigned short f2bf(float f) {
  union { float f; unsigned int u; } v;
  v.f = f;
  unsigned int u = v.u;
  return (unsigned short)((u + 0x7FFFu + ((u >> 16) & 1u)) >> 16);
}

union BFrag { unsigned short u[8]; unsigned int w[4]; bf16x8 v; };

__device__ __forceinline__ f32x16 mfma32(bf16x8 a, bf16x8 b, f32x16 c) {
  return __builtin_amdgcn_mfma_f32_32x32x16_bf16(a, b, c, 0, 0, 0);
}

// ---------------- x gather + fp32->bf16 (region-token order) ----------------
__global__ __launch_bounds__(256) void k_xgather(const float* __restrict__ x,
                                                 unsigned short* __restrict__ xb) {
  int idx = blockIdx.x * 256 + threadIdx.x;   // 36864*64 threads, 8 elems each
  int m = idx >> 6;
  int seg = (idx & 63) << 3;
  int r = m >> 8, n = m & 255;
  int a = r / 12, b = r - a * 12;
  int ii = n >> 4, jj = n & 15;
  long g = (long)((a * 16 + ii) * 192 + b * 16 + jj);
  const float4* p = (const float4*)(x + g * 512 + seg);
  float4 v0 = p[0], v1 = p[1];
  union { unsigned short u[8]; int4 v; } o;
  o.u[0] = f2bf(v0.x); o.u[1] = f2bf(v0.y); o.u[2] = f2bf(v0.z); o.u[3] = f2bf(v0.w);
  o.u[4] = f2bf(v1.x); o.u[5] = f2bf(v1.y); o.u[6] = f2bf(v1.z); o.u[7] = f2bf(v1.w);
  *(int4*)(xb + (size_t)m * 512 + seg) = o.v;
}

// ---------------- plain fp32->bf16 ----------------
__global__ __launch_bounds__(256) void k_cvt(const float* __restrict__ s,
                                             unsigned short* __restrict__ d, int n8) {
  int i = blockIdx.x * 256 + threadIdx.x;
  if (i >= n8) return;
  const float4* p = (const float4*)(s + (size_t)i * 8);
  float4 a = p[0], b = p[1];
  union { unsigned short u[8]; int4 v; } o;
  o.u[0] = f2bf(a.x); o.u[1] = f2bf(a.y); o.u[2] = f2bf(a.z); o.u[3] = f2bf(a.w);
  o.u[4] = f2bf(b.x); o.u[5] = f2bf(b.y); o.u[6] = f2bf(b.z); o.u[7] = f2bf(b.w);
  *(int4*)(d + (size_t)i * 8) = o.v;
}

// ---------------- GEMM: C[m][n] = sum_k A[m][k]*B[n][k]  (B given row-major [N][K]) ----
// MODE 0: QKV epilogue -> scatter to q/k/vt buffers (q scaled by 0.125)
// MODE 1: proj epilogue -> scatter fp32 to d_out in original token order
template<int MODE>
__global__ __launch_bounds__(256, 2) void k_gemm(
    const unsigned short* __restrict__ A, const unsigned short* __restrict__ B,
    const float* __restrict__ bias,
    unsigned short* __restrict__ qb, unsigned short* __restrict__ kb,
    unsigned short* __restrict__ vtb, float* __restrict__ out) {
  __shared__ unsigned short As[8192];   // [128][64]
  __shared__ unsigned short Bs[8192];   // [128][64]
  int t = threadIdx.x;
  int bn = blockIdx.x, bm = blockIdx.y;
  int w = t >> 6, lane = t & 63;
  int l31 = lane & 31, lh = lane >> 5;
  int wr = w >> 1, wc = w & 1;
  f32x16 acc[2][2];
  for (int i = 0; i < 2; ++i)
    for (int j = 0; j < 2; ++j)
      for (int e = 0; e < 16; ++e) acc[i][j][e] = 0.0f;

  for (int ks = 0; ks < 8; ++ks) {
    const unsigned short* Ag = A + (size_t)(bm * 128) * 512 + ks * 64;
    const unsigned short* Bg = B + (size_t)(bn * 128) * 512 + ks * 64;
#pragma unroll
    for (int p = 0; p < 4; ++p) {
      int c = p * 256 + t;
      int row = c >> 3, cc = c & 7;
      ((int4*)As)[c] = *(const int4*)(Ag + (size_t)row * 512 + cc * 8);
      ((int4*)Bs)[c] = *(const int4*)(Bg + (size_t)row * 512 + cc * 8);
    }
    __syncthreads();
#pragma unroll
    for (int kt = 0; kt < 4; ++kt) {
      bf16x8 af[2], bf[2];
#pragma unroll
      for (int mt = 0; mt < 2; ++mt)
        af[mt] = *(const bf16x8*)((const char*)As + ((wr * 64 + mt * 32 + l31) * 128 + kt * 32 + lh * 16));
#pragma unroll
      for (int nt = 0; nt < 2; ++nt)
        bf[nt] = *(const bf16x8*)((const char*)Bs + ((wc * 64 + nt * 32 + l31) * 128 + kt * 32 + lh * 16));
#pragma unroll
      for (int mt = 0; mt < 2; ++mt)
#pragma unroll
        for (int nt = 0; nt < 2; ++nt)
          acc[mt][nt] = mfma32(af[mt], bf[nt], acc[mt][nt]);
    }
    __syncthreads();
  }

  int nBase = bn * 128 + wc * 64;
  int mBase = bm * 128 + wr * 64;
#pragma unroll
  for (int nt = 0; nt < 2; ++nt) {
    int nn = nBase + nt * 32 + l31;
    float bs = bias[nn];
    if (MODE == 0) {
      int tsel = nn >> 9, rem = nn & 511;
      int hh = rem >> 6, d = rem & 63;
#pragma unroll
      for (int mt = 0; mt < 2; ++mt) {
#pragma unroll
        for (int q = 0; q < 4; ++q) {
          int m0 = mBase + mt * 32 + q * 8 + lh * 4;
          int r = m0 >> 8, tok = m0 & 255;
          size_t base = (size_t)(r * 8 + hh) * 16384;
          if (tsel == 0) {
#pragma unroll
            for (int j = 0; j < 4; ++j)
              qb[base + (size_t)(tok + j) * 64 + d] = f2bf((acc[mt][nt][q * 4 + j] + bs) * 0.125f);
          } else if (tsel == 1) {
#pragma unroll
            for (int j = 0; j < 4; ++j)
              kb[base + (size_t)(tok + j) * 64 + d] = f2bf(acc[mt][nt][q * 4 + j] + bs);
          } else {
            unsigned long long pv = 0;
#pragma unroll
            for (int j = 0; j < 4; ++j)
              pv |= (unsigned long long)f2bf(acc[mt][nt][q * 4 + j] + bs) << (16 * j);
            *(unsigned long long*)(vtb + base + (size_t)d * 256 + tok) = pv;
          }
        }
      }
    } else {
#pragma unroll
      for (int mt = 0; mt < 2; ++mt) {
#pragma unroll
        for (int q = 0; q < 4; ++q) {
          int m0 = mBase + mt * 32 + q * 8 + lh * 4;
          int r = m0 >> 8;
          int a = r / 12, bcol = r - a * 12;
#pragma unroll
          for (int j = 0; j < 4; ++j) {
            int tok = (m0 & 255) + j;
            int ii = tok >> 4, jj = tok & 15;
            long gg = (long)((a * 16 + ii) * 192 + bcol * 16 + jj);
            out[gg * 512 + nn] = acc[mt][nt][q * 4 + j] + bs;
          }
        }
      }
    }
  }
}

// ---------------- fused region attention per (region, head) ----------------
// LDS: [0,32K) Q swz [256][64]; [32K,64K) K swz; later [0,128K) S^T bf16 [j][i] swz;
//      [128K,160K) V^T swz [64][256]
__global__ __launch_bounds__(512, 2) void k_attn(
    const unsigned short* __restrict__ qb, const unsigned short* __restrict__ kb,
    const unsigned short* __restrict__ vtb, const float* __restrict__ pe_w,
    unsigned short* __restrict__ ctxb) {
  extern __shared__ char lds[];
  int rh = blockIdx.x;
  int h = rh & 7;
  int t = threadIdx.x, w = t >> 6, lane = t & 63;
  int l31 = lane & 31, lh = lane >> 5;
  int qi = (w << 5) + l31;          // this wave's output row block: i = qi

  const unsigned short* Qg = qb + (size_t)rh * 16384;
  const unsigned short* Kg = kb + (size_t)rh * 16384;
  const unsigned short* Vg = vtb + (size_t)rh * 16384;

#pragma unroll
  for (int p = 0; p < 4; ++p) {
    int c = p * 512 + t;
    int row = c >> 3, cc = c & 7;
    int4 vq = *(const int4*)(Qg + (size_t)row * 64 + cc * 8);
    int4 vk = *(const int4*)(Kg + (size_t)row * 64 + cc * 8);
    int so = row * 128 + ((cc ^ (row & 7)) << 4);
    *(int4*)(lds + so) = vq;
    *(int4*)(lds + 32768 + so) = vk;
  }
#pragma unroll
  for (int p = 0; p < 4; ++p) {
    int c = p * 512 + t;
    int row = c >> 5, cc = c & 31;
    int4 vv = *(const int4*)(Vg + (size_t)row * 256 + cc * 8);
    *(int4*)(lds + 131072 + row * 512 + ((cc ^ (row & 7)) << 4)) = vv;
  }
  __syncthreads();

  // S^T[j][i] = sum_d K[j][d] * Qs[i][d]   (Q pre-scaled by 1/8)
  f32x16 acc[8];
#pragma unroll
  for (int mt = 0; mt < 8; ++mt)
    for (int e = 0; e < 16; ++e) acc[mt][e] = 0.0f;

  bf16x8 bq[4];
#pragma unroll
  for (int kt = 0; kt < 4; ++kt)
    bq[kt] = *(const bf16x8*)(lds + (qi * 128 + (((kt * 2 + lh) ^ (qi & 7)) << 4)));

#pragma unroll
  for (int mt = 0; mt < 8; ++mt) {
    int kj = (mt << 5) + l31;
    int rb = 32768 + kj * 128;
#pragma unroll
    for (int kt = 0; kt < 4; ++kt) {
      bf16x8 ak = *(const bf16x8*)(lds + (rb + (((kt * 2 + lh) ^ (kj & 7)) << 4)));
      acc[mt] = mfma32(ak, bq[kt], acc[mt]);
    }
  }
  __syncthreads();   // done reading Q/K -> reuse [0,128K) for S^T

  // store S^T bf16 to LDS (for the conv contraction over i')
#pragma unroll
  for (int mt = 0; mt < 8; ++mt) {
#pragma unroll
    for (int rg = 0; rg < 16; ++rg) {
      int j = (mt << 5) + (rg & 3) + ((rg >> 2) << 3) + (lh << 2);
      int byte = (j * 512 + qi * 2) ^ ((j & 7) << 4);
      *(unsigned short*)(lds + byte) = f2bf(acc[mt][rg]);
    }
  }
  __syncthreads();

  // pe^T[j][i] += sum_{i'} S^T[j][i'] * wband(i'-i+7); band B generated in regs
  const float* wh = pe_w + h * 15;
#pragma unroll
  for (int kt4 = 0; kt4 < 4; ++kt4) {
    int ktg = 2 * w - 1 + kt4;
    if (ktg >= 0 && ktg <= 15) {
      BFrag bb;
#pragma unroll
      for (int e = 0; e < 8; ++e) {
        int ip = (ktg << 4) + (lh << 3) + e;
        int diff = ip - qi + 7;
        float val = (diff >= 0 && diff <= 14) ? wh[diff] : 0.0f;
        bb.u[e] = f2bf(val);
      }
#pragma unroll
      for (int mt = 0; mt < 8; ++mt) {
        int j = (mt << 5) + l31;
        int byte = (j * 512 + (ktg << 5) + (lh << 4)) ^ ((j & 7) << 4);
        bf16x8 aa = *(const bf16x8*)(lds + byte);
        acc[mt] = mfma32(aa, bb.v, acc[mt]);
      }
    }
  }

  // softmax over j (lane holds 128 of 256 entries for its row i; pair with lane^32)
  float mx = -3.0e38f;
#pragma unroll
  for (int mt = 0; mt < 8; ++mt)
#pragma unroll
    for (int e = 0; e < 16; ++e) mx = fmaxf(mx, acc[mt][e]);
  mx = fmaxf(mx, __shfl_xor(mx, 32));
  float sum = 0.0f;
#pragma unroll
  for (int mt = 0; mt < 8; ++mt)
#pragma unroll
    for (int e = 0; e < 16; ++e) {
      float pp = __expf(acc[mt][e] - mx);
      acc[mt][e] = pp;
      sum += pp;
    }
  sum += __shfl_xor(sum, 32);
  float inv = 1.0f / sum;

  // PV: out[i][d] = sum_j P[i][j] V[j][d]; P fragments assembled in-register
  f32x16 acco[2];
  for (int nt = 0; nt < 2; ++nt)
    for (int e = 0; e < 16; ++e) acco[nt][e] = 0.0f;

#pragma unroll
  for (int mt = 0; mt < 8; ++mt) {
    unsigned int pk[8], sw[8];
#pragma unroll
    for (int u = 0; u < 8; ++u) {
      float lo = acc[mt][2 * u] * inv, hi = acc[mt][2 * u + 1] * inv;
      pk[u] = (unsigned int)f2bf(lo) | ((unsigned int)f2bf(hi) << 16);
    }
#pragma unroll
    for (int u = 0; u < 8; ++u) sw[u] = (unsigned int)__shfl_xor((int)pk[u], 32);
    BFrag f0, f1;
    if (lh == 0) {
      f0.w[0] = pk[0]; f0.w[1] = pk[1]; f0.w[2] = sw[0]; f0.w[3] = sw[1];
      f1.w[0] = pk[4]; f1.w[1] = pk[5]; f1.w[2] = sw[4]; f1.w[3] = sw[5];
    } else {
      f0.w[0] = sw[2]; f0.w[1] = sw[3]; f0.w[2] = pk[2]; f0.w[3] = pk[3];
      f1.w[0] = sw[6]; f1.w[1] = sw[7]; f1.w[2] = pk[6]; f1.w[3] = pk[7];
    }
#pragma unroll
    for (int nt = 0; nt < 2; ++nt) {
      int d = (nt << 5) + l31;
      int base = 131072 + d * 512;
      bf16x8 bv0 = *(const bf16x8*)(lds + base + (((mt << 6) + (lh << 4)) ^ ((d & 7) << 4)));
      bf16x8 bv1 = *(const bf16x8*)(lds + base + (((mt << 6) + 32 + (lh << 4)) ^ ((d & 7) << 4)));
      acco[nt] = mfma32(f0.v, bv0, acco[nt]);
      acco[nt] = mfma32(f1.v, bv1, acco[nt]);
    }
  }

  // write ctx bf16 [36864][512], channel = h*64 + d
  int r = rh >> 3;
#pragma unroll
  for (int nt = 0; nt < 2; ++nt) {
    int d = h * 64 + (nt << 5) + l31;
#pragma unroll
    for (int rg = 0; rg < 16; ++rg) {
      int i = (w << 5) + (rg & 3) + ((rg >> 2) << 3) + (lh << 2);
      ctxb[(size_t)(r * 256 + i) * 512 + d] = f2bf(acco[nt][rg]);
    }
  }
}

extern "C" void kernel_launch(void* const* d_in, const int* in_sizes, int n_in,
                              void* d_out, int out_size, void* d_ws, size_t ws_size,
                              hipStream_t stream) {
  const float* x = (const float*)d_in[0];
  const float* Wqkv = (const float*)d_in[1];
  const float* bqkv = (const float*)d_in[2];
  const float* Wproj = (const float*)d_in[3];
  const float* bproj = (const float*)d_in[4];
  const float* pew = (const float*)d_in[5];
  // d_in[6] = pe_b: constant per softmax row -> cancels exactly; skipped.

  char* ws = (char*)d_ws;
  unsigned short* xb = (unsigned short*)ws;                       // 37,748,736 B; later reused as ctx
  unsigned short* wqkvb = (unsigned short*)(ws + 37748736);       // 1,572,864 B
  unsigned short* wprojb = (unsigned short*)(ws + 39321600);      // 524,288 B
  unsigned short* qb = (unsigned short*)(ws + 39845888);          // 37,748,736 B
  unsigned short* kb = (unsigned short*)(ws + 77594624);          // 37,748,736 B
  unsigned short* vtb = (unsigned short*)(ws + 115343360);        // 37,748,736 B  (end 153,092,096)

  (void)hipFuncSetAttribute((const void*)k_attn,
                            hipFuncAttributeMaxDynamicSharedMemorySize, 163840);

  k_xgather<<<9216, 256, 0, stream>>>(x, xb);
  k_cvt<<<384, 256, 0, stream>>>(Wqkv, wqkvb, 98304);
  k_cvt<<<128, 256, 0, stream>>>(Wproj, wprojb, 32768);
  k_gemm<0><<<dim3(12, 288), 256, 0, stream>>>(xb, wqkvb, bqkv, qb, kb, vtb, nullptr);
  k_attn<<<1152, 512, 163840, stream>>>(qb, kb, vtb, pew, xb);
  k_gemm<1><<<dim3(4, 288), 256, 0, stream>>>(xb, wprojb, bproj, nullptr, nullptr, nullptr,
                                              (float*)d_out);
}

// Round 2
// 222.460 us; speedup vs baseline: 1.3125x; 1.3125x over previous
//
#include <hip/hip_runtime.h>
#include <stdint.h>

typedef __attribute__((ext_vector_type(8))) __bf16 bf16x8;
typedef __attribute__((ext_vector_type(16))) float f32x16;

__device__ __forceinline__ unsigned short f2bf(float f) {
  union { float f; unsigned int u; } v;
  v.f = f;
  unsigned int u = v.u;
  return (unsigned short)((u + 0x7FFFu + ((u >> 16) & 1u)) >> 16);
}

union BFrag { unsigned short u[8]; unsigned int w[4]; bf16x8 v; };

__device__ __forceinline__ f32x16 mfma32(bf16x8 a, bf16x8 b, f32x16 c) {
  return __builtin_amdgcn_mfma_f32_32x32x16_bf16(a, b, c, 0, 0, 0);
}

#define GLOAD_LDS16(gptr, lptr)                                                \
  __builtin_amdgcn_global_load_lds(                                           \
      (const __attribute__((address_space(1))) void*)(gptr),                  \
      (__attribute__((address_space(3))) void*)(lptr), 16, 0, 0)

// ---------------- x gather + fp32->bf16 (region-token order) ----------------
__global__ __launch_bounds__(256) void k_xgather(const float* __restrict__ x,
                                                 unsigned short* __restrict__ xb) {
  int idx = blockIdx.x * 256 + threadIdx.x;   // 36864*64 threads, 8 elems each
  int m = idx >> 6;
  int seg = (idx & 63) << 3;
  int r = m >> 8, n = m & 255;
  int a = r / 12, b = r - a * 12;
  int ii = n >> 4, jj = n & 15;
  long g = (long)((a * 16 + ii) * 192 + b * 16 + jj);
  const float4* p = (const float4*)(x + g * 512 + seg);
  float4 v0 = p[0], v1 = p[1];
  union { unsigned short u[8]; int4 v; } o;
  o.u[0] = f2bf(v0.x); o.u[1] = f2bf(v0.y); o.u[2] = f2bf(v0.z); o.u[3] = f2bf(v0.w);
  o.u[4] = f2bf(v1.x); o.u[5] = f2bf(v1.y); o.u[6] = f2bf(v1.z); o.u[7] = f2bf(v1.w);
  *(int4*)(xb + (size_t)m * 512 + seg) = o.v;
}

// ---------------- plain fp32->bf16 ----------------
__global__ __launch_bounds__(256) void k_cvt(const float* __restrict__ s,
                                             unsigned short* __restrict__ d, int n8) {
  int i = blockIdx.x * 256 + threadIdx.x;
  if (i >= n8) return;
  const float4* p = (const float4*)(s + (size_t)i * 8);
  float4 a = p[0], b = p[1];
  union { unsigned short u[8]; int4 v; } o;
  o.u[0] = f2bf(a.x); o.u[1] = f2bf(a.y); o.u[2] = f2bf(a.z); o.u[3] = f2bf(a.w);
  o.u[4] = f2bf(b.x); o.u[5] = f2bf(b.y); o.u[6] = f2bf(b.z); o.u[7] = f2bf(b.w);
  *(int4*)(d + (size_t)i * 8) = o.v;
}

// ---------------- GEMM: C[m][n] = sum_k A[m][k]*B[n][k]  (B row-major [N][K]) ----
// m97-style: global_load_lds staging (linear LDS dest, pre-swizzled global col),
// XOR-swizzled ds_read_b128 frag loads, XCD-chunked block swizzle.
// MODE 0: QKV epilogue -> scatter to q/k/vt buffers (q scaled by 0.125)
// MODE 1: proj epilogue -> scatter fp32 to d_out in original token order
template<int MODE, int NBN>
__global__ __launch_bounds__(256, 2) void k_gemm(
    const unsigned short* __restrict__ A, const unsigned short* __restrict__ B,
    const float* __restrict__ bias,
    unsigned short* __restrict__ qb, unsigned short* __restrict__ kb,
    unsigned short* __restrict__ vtb, float* __restrict__ out) {
  __shared__ unsigned short As[8192];   // [128][64] bf16, col-swizzled content
  __shared__ unsigned short Bs[8192];
  int t = threadIdx.x;
  // bijective XCD-chunked swizzle (nwg % 8 == 0)
  constexpr int NWG = NBN * 288;
  int d0 = blockIdx.x;
  int tl = (d0 & 7) * (NWG >> 3) + (d0 >> 3);
  int bm = tl / NBN, bn = tl % NBN;

  int w = t >> 6, lane = t & 63;
  int l31 = lane & 31, lh = lane >> 5;
  int wr = w >> 1, wc = w & 1;

  // staging coords: thread t stages row srow(+32*rnd), 16B col segment cseg
  int srow = t >> 3, cseg = t & 7;
  int csw = (cseg ^ (srow & 7)) << 3;       // swizzled source column (elements)
  int ldsWaveOff = (t >> 6) << 10;          // wave-uniform byte base

  f32x16 acc[2][2];
  for (int i = 0; i < 2; ++i)
    for (int j = 0; j < 2; ++j)
      for (int e = 0; e < 16; ++e) acc[i][j][e] = 0.0f;

  const unsigned short* Ag = A + (size_t)(bm * 128 + srow) * 512 + csw;
  const unsigned short* Bg = B + (size_t)(bn * 128 + srow) * 512 + csw;

  for (int ks = 0; ks < 8; ++ks) {
#pragma unroll
    for (int rnd = 0; rnd < 4; ++rnd) {
      GLOAD_LDS16(Ag + (size_t)rnd * 32 * 512 + ks * 64,
                  (char*)As + ldsWaveOff + rnd * 4096);
      GLOAD_LDS16(Bg + (size_t)rnd * 32 * 512 + ks * 64,
                  (char*)Bs + ldsWaveOff + rnd * 4096);
    }
    __syncthreads();   // drains vmcnt+lgkmcnt
#pragma unroll
    for (int kt = 0; kt < 4; ++kt) {
      bf16x8 af[2], bfr[2];
#pragma unroll
      for (int mt = 0; mt < 2; ++mt) {
        int r = wr * 64 + mt * 32 + l31;
        af[mt] = *(const bf16x8*)((const char*)As + r * 128 +
                                  ((kt * 32 + lh * 16) ^ ((r & 7) << 4)));
      }
#pragma unroll
      for (int nt = 0; nt < 2; ++nt) {
        int r = wc * 64 + nt * 32 + l31;
        bfr[nt] = *(const bf16x8*)((const char*)Bs + r * 128 +
                                   ((kt * 32 + lh * 16) ^ ((r & 7) << 4)));
      }
#pragma unroll
      for (int mt = 0; mt < 2; ++mt)
#pragma unroll
        for (int nt = 0; nt < 2; ++nt)
          acc[mt][nt] = mfma32(af[mt], bfr[nt], acc[mt][nt]);
    }
    __syncthreads();
  }

  int nBase = bn * 128 + wc * 64;
  int mBase = bm * 128 + wr * 64;
#pragma unroll
  for (int nt = 0; nt < 2; ++nt) {
    int nn = nBase + nt * 32 + l31;
    float bs = bias[nn];
    if (MODE == 0) {
      int tsel = nn >> 9, rem = nn & 511;
      int hh = rem >> 6, d = rem & 63;
#pragma unroll
      for (int mt = 0; mt < 2; ++mt) {
#pragma unroll
        for (int q = 0; q < 4; ++q) {
          int m0 = mBase + mt * 32 + q * 8 + lh * 4;
          int r = m0 >> 8, tok = m0 & 255;
          size_t base = (size_t)(r * 8 + hh) * 16384;
          if (tsel == 0) {
#pragma unroll
            for (int j = 0; j < 4; ++j)
              qb[base + (size_t)(tok + j) * 64 + d] = f2bf((acc[mt][nt][q * 4 + j] + bs) * 0.125f);
          } else if (tsel == 1) {
#pragma unroll
            for (int j = 0; j < 4; ++j)
              kb[base + (size_t)(tok + j) * 64 + d] = f2bf(acc[mt][nt][q * 4 + j] + bs);
          } else {
            unsigned long long pv = 0;
#pragma unroll
            for (int j = 0; j < 4; ++j)
              pv |= (unsigned long long)f2bf(acc[mt][nt][q * 4 + j] + bs) << (16 * j);
            *(unsigned long long*)(vtb + base + (size_t)d * 256 + tok) = pv;
          }
        }
      }
    } else {
#pragma unroll
      for (int mt = 0; mt < 2; ++mt) {
#pragma unroll
        for (int q = 0; q < 4; ++q) {
          int m0 = mBase + mt * 32 + q * 8 + lh * 4;
          int r = m0 >> 8;
          int a = r / 12, bcol = r - a * 12;
#pragma unroll
          for (int j = 0; j < 4; ++j) {
            int tok = (m0 & 255) + j;
            int ii = tok >> 4, jj = tok & 15;
            long gg = (long)((a * 16 + ii) * 192 + bcol * 16 + jj);
            out[gg * 512 + nn] = acc[mt][nt][q * 4 + j] + bs;
          }
        }
      }
    }
  }
}

// ---------------- fused region attention per (region, head) ----------------
// LDS: [0,32K) Q swz [256][64]; [32K,64K) K swz; later [0,128K) S^T bf16 [j][i] swz;
//      [128K,160K) V^T swz [64][256]
__global__ __launch_bounds__(512, 2) void k_attn(
    const unsigned short* __restrict__ qb, const unsigned short* __restrict__ kb,
    const unsigned short* __restrict__ vtb, const float* __restrict__ pe_w,
    unsigned short* __restrict__ ctxb) {
  extern __shared__ char lds[];
  int rh = blockIdx.x;
  int h = rh & 7;
  int t = threadIdx.x, w = t >> 6, lane = t & 63;
  int l31 = lane & 31, lh = lane >> 5;
  int qi = (w << 5) + l31;          // this wave's output row block: i = qi

  const unsigned short* Qg = qb + (size_t)rh * 16384;
  const unsigned short* Kg = kb + (size_t)rh * 16384;
  const unsigned short* Vg = vtb + (size_t)rh * 16384;

#pragma unroll
  for (int p = 0; p < 4; ++p) {
    int c = p * 512 + t;
    int row = c >> 3, cc = c & 7;
    int4 vq = *(const int4*)(Qg + (size_t)row * 64 + cc * 8);
    int4 vk = *(const int4*)(Kg + (size_t)row * 64 + cc * 8);
    int so = row * 128 + ((cc ^ (row & 7)) << 4);
    *(int4*)(lds + so) = vq;
    *(int4*)(lds + 32768 + so) = vk;
  }
#pragma unroll
  for (int p = 0; p < 4; ++p) {
    int c = p * 512 + t;
    int row = c >> 5, cc = c & 31;
    int4 vv = *(const int4*)(Vg + (size_t)row * 256 + cc * 8);
    *(int4*)(lds + 131072 + row * 512 + ((cc ^ (row & 7)) << 4)) = vv;
  }
  __syncthreads();

  // S^T[j][i] = sum_d K[j][d] * Qs[i][d]   (Q pre-scaled by 1/8)
  f32x16 acc[8];
#pragma unroll
  for (int mt = 0; mt < 8; ++mt)
    for (int e = 0; e < 16; ++e) acc[mt][e] = 0.0f;

  bf16x8 bq[4];
#pragma unroll
  for (int kt = 0; kt < 4; ++kt)
    bq[kt] = *(const bf16x8*)(lds + (qi * 128 + (((kt * 2 + lh) ^ (qi & 7)) << 4)));

#pragma unroll
  for (int mt = 0; mt < 8; ++mt) {
    int kj = (mt << 5) + l31;
    int rb = 32768 + kj * 128;
#pragma unroll
    for (int kt = 0; kt < 4; ++kt) {
      bf16x8 ak = *(const bf16x8*)(lds + (rb + (((kt * 2 + lh) ^ (kj & 7)) << 4)));
      acc[mt] = mfma32(ak, bq[kt], acc[mt]);
    }
  }
  __syncthreads();   // done reading Q/K -> reuse [0,128K) for S^T

  // store S^T bf16 to LDS (for the conv contraction over i')
#pragma unroll
  for (int mt = 0; mt < 8; ++mt) {
#pragma unroll
    for (int rg = 0; rg < 16; ++rg) {
      int j = (mt << 5) + (rg & 3) + ((rg >> 2) << 3) + (lh << 2);
      int byte = (j * 512 + qi * 2) ^ ((j & 7) << 4);
      *(unsigned short*)(lds + byte) = f2bf(acc[mt][rg]);
    }
  }
  __syncthreads();

  // pe^T[j][i] += sum_{i'} S^T[j][i'] * wband(i'-i+7); band B generated in regs
  const float* wh = pe_w + h * 15;
#pragma unroll
  for (int kt4 = 0; kt4 < 4; ++kt4) {
    int ktg = 2 * w - 1 + kt4;
    if (ktg >= 0 && ktg <= 15) {
      BFrag bb;
#pragma unroll
      for (int e = 0; e < 8; ++e) {
        int ip = (ktg << 4) + (lh << 3) + e;
        int diff = ip - qi + 7;
        float val = (diff >= 0 && diff <= 14) ? wh[diff] : 0.0f;
        bb.u[e] = f2bf(val);
      }
#pragma unroll
      for (int mt = 0; mt < 8; ++mt) {
        int j = (mt << 5) + l31;
        int byte = (j * 512 + (ktg << 5) + (lh << 4)) ^ ((j & 7) << 4);
        bf16x8 aa = *(const bf16x8*)(lds + byte);
        acc[mt] = mfma32(aa, bb.v, acc[mt]);
      }
    }
  }

  // softmax over j (lane holds 128 of 256 entries for its row i; pair with lane^32)
  float mx = -3.0e38f;
#pragma unroll
  for (int mt = 0; mt < 8; ++mt)
#pragma unroll
    for (int e = 0; e < 16; ++e) mx = fmaxf(mx, acc[mt][e]);
  mx = fmaxf(mx, __shfl_xor(mx, 32));
  float sum = 0.0f;
#pragma unroll
  for (int mt = 0; mt < 8; ++mt)
#pragma unroll
    for (int e = 0; e < 16; ++e) {
      float pp = __expf(acc[mt][e] - mx);
      acc[mt][e] = pp;
      sum += pp;
    }
  sum += __shfl_xor(sum, 32);
  float inv = 1.0f / sum;

  // PV: out[i][d] = sum_j P[i][j] V[j][d]; P fragments assembled in-register
  f32x16 acco[2];
  for (int nt = 0; nt < 2; ++nt)
    for (int e = 0; e < 16; ++e) acco[nt][e] = 0.0f;

#pragma unroll
  for (int mt = 0; mt < 8; ++mt) {
    unsigned int pk[8], sw[8];
#pragma unroll
    for (int u = 0; u < 8; ++u) {
      float lo = acc[mt][2 * u] * inv, hi = acc[mt][2 * u + 1] * inv;
      pk[u] = (unsigned int)f2bf(lo) | ((unsigned int)f2bf(hi) << 16);
    }
#pragma unroll
    for (int u = 0; u < 8; ++u) sw[u] = (unsigned int)__shfl_xor((int)pk[u], 32);
    BFrag f0, f1;
    if (lh == 0) {
      f0.w[0] = pk[0]; f0.w[1] = pk[1]; f0.w[2] = sw[0]; f0.w[3] = sw[1];
      f1.w[0] = pk[4]; f1.w[1] = pk[5]; f1.w[2] = sw[4]; f1.w[3] = sw[5];
    } else {
      f0.w[0] = sw[2]; f0.w[1] = sw[3]; f0.w[2] = pk[2]; f0.w[3] = pk[3];
      f1.w[0] = sw[6]; f1.w[1] = sw[7]; f1.w[2] = pk[6]; f1.w[3] = pk[7];
    }
#pragma unroll
    for (int nt = 0; nt < 2; ++nt) {
      int d = (nt << 5) + l31;
      int base = 131072 + d * 512;
      bf16x8 bv0 = *(const bf16x8*)(lds + base + (((mt << 6) + (lh << 4)) ^ ((d & 7) << 4)));
      bf16x8 bv1 = *(const bf16x8*)(lds + base + (((mt << 6) + 32 + (lh << 4)) ^ ((d & 7) << 4)));
      acco[nt] = mfma32(f0.v, bv0, acco[nt]);
      acco[nt] = mfma32(f1.v, bv1, acco[nt]);
    }
  }

  // write ctx bf16 [36864][512], channel = h*64 + d
  int r = rh >> 3;
#pragma unroll
  for (int nt = 0; nt < 2; ++nt) {
    int d = h * 64 + (nt << 5) + l31;
#pragma unroll
    for (int rg = 0; rg < 16; ++rg) {
      int i = (w << 5) + (rg & 3) + ((rg >> 2) << 3) + (lh << 2);
      ctxb[(size_t)(r * 256 + i) * 512 + d] = f2bf(acco[nt][rg]);
    }
  }
}

extern "C" void kernel_launch(void* const* d_in, const int* in_sizes, int n_in,
                              void* d_out, int out_size, void* d_ws, size_t ws_size,
                              hipStream_t stream) {
  const float* x = (const float*)d_in[0];
  const float* Wqkv = (const float*)d_in[1];
  const float* bqkv = (const float*)d_in[2];
  const float* Wproj = (const float*)d_in[3];
  const float* bproj = (const float*)d_in[4];
  const float* pew = (const float*)d_in[5];
  // d_in[6] = pe_b: constant per softmax row -> cancels exactly; skipped.

  char* ws = (char*)d_ws;
  unsigned short* xb = (unsigned short*)ws;                       // 37,748,736 B; later reused as ctx
  unsigned short* wqkvb = (unsigned short*)(ws + 37748736);       // 1,572,864 B
  unsigned short* wprojb = (unsigned short*)(ws + 39321600);      // 524,288 B
  unsigned short* qb = (unsigned short*)(ws + 39845888);          // 37,748,736 B
  unsigned short* kb = (unsigned short*)(ws + 77594624);          // 37,748,736 B
  unsigned short* vtb = (unsigned short*)(ws + 115343360);        // 37,748,736 B  (end 153,092,096)

  (void)hipFuncSetAttribute((const void*)k_attn,
                            hipFuncAttributeMaxDynamicSharedMemorySize, 163840);

  k_xgather<<<9216, 256, 0, stream>>>(x, xb);
  k_cvt<<<384, 256, 0, stream>>>(Wqkv, wqkvb, 98304);
  k_cvt<<<128, 256, 0, stream>>>(Wproj, wprojb, 32768);
  k_gemm<0, 12><<<3456, 256, 0, stream>>>(xb, wqkvb, bqkv, qb, kb, vtb, nullptr);
  k_attn<<<1152, 512, 163840, stream>>>(qb, kb, vtb, pew, xb);
  k_gemm<1, 4><<<1152, 256, 0, stream>>>(xb, wprojb, bproj, nullptr, nullptr, nullptr,
                                         (float*)d_out);
}